// Round 3
// baseline (124.055 us; speedup 1.0000x reference)
//
#include <hip/hip_runtime.h>
#include <cmath>

#define VOCAB   50257
#define HIDDEN  16
#define BATCH   256
#define SEQLEN  8192
#define TCHUNKS 8          // T split for K2 parallelism; chunks merged by atomicAdd
#define K3_BCHUNK 64       // batch rows per K3 block

// ---------------------------------------------------------------------------
// K1: per-vocab fused table  c[v][k] = sigmoid(Wg.e+bg) * tanh((Wu^T e)[k]+bu[k])
// One thread per vocab row. Also zero-inits the 256x16 memory accumulator
// (blocks 0..15) so K2 can atomicAdd into it — ws is poisoned 0xAA each call.
// ---------------------------------------------------------------------------
__global__ __launch_bounds__(256) void k1_build_table(
    const float* __restrict__ embed, const float* __restrict__ Wg,
    const float* __restrict__ bg,    const float* __restrict__ Wu,
    const float* __restrict__ bu,    float* __restrict__ ctab,
    float* __restrict__ mem_acc)
{
    __shared__ float sWu[256], sWg[16], sbu[16];
    const int tid = threadIdx.x;
    sWu[tid] = Wu[tid];
    if (tid < 16) { sWg[tid] = Wg[tid]; sbu[tid] = bu[tid]; }
    if (blockIdx.x < (BATCH * HIDDEN) / 256)              // 16 blocks zero 4096 floats
        mem_acc[blockIdx.x * 256 + tid] = 0.f;
    __syncthreads();

    const int v = blockIdx.x * 256 + tid;
    if (v >= VOCAB) return;

    const float4* er = (const float4*)(embed + (size_t)v * HIDDEN);
    float4 e0 = er[0], e1 = er[1], e2 = er[2], e3 = er[3];
    float e[16] = {e0.x,e0.y,e0.z,e0.w, e1.x,e1.y,e1.z,e1.w,
                   e2.x,e2.y,e2.z,e2.w, e3.x,e3.y,e3.z,e3.w};

    float z = bg[0];
#pragma unroll
    for (int h = 0; h < 16; ++h) z = fmaf(e[h], sWg[h], z);
    const float g = 1.0f / (1.0f + __expf(-z));

    float o[16];
#pragma unroll
    for (int k = 0; k < 16; ++k) {
        float u = sbu[k];
#pragma unroll
        for (int h = 0; h < 16; ++h) u = fmaf(e[h], sWu[h * 16 + k], u);
        o[k] = g * tanhf(u);
    }

    float4* cr = (float4*)(ctab + (size_t)v * HIDDEN);
    cr[0] = make_float4(o[0],  o[1],  o[2],  o[3]);
    cr[1] = make_float4(o[4],  o[5],  o[6],  o[7]);
    cr[2] = make_float4(o[8],  o[9],  o[10], o[11]);
    cr[3] = make_float4(o[12], o[13], o[14], o[15]);
}

// ---------------------------------------------------------------------------
// K2: mem_acc[b] += sum_t c[seq[b,t]] — gather-sum over L2-resident table.
// 4-lane-cooperative gather (16 contiguous 64 B segments per wave instr).
// Final per-block 16-float partial goes out as 16 device-scope atomicAdds.
// ---------------------------------------------------------------------------
__global__ __launch_bounds__(256) void k2_accum(
    const int* __restrict__ seq, const float* __restrict__ ctab,
    float* __restrict__ mem_acc)
{
    const int b = blockIdx.x, chunk = blockIdx.y, tid = threadIdx.x;
    constexpr int TPC = SEQLEN / TCHUNKS;                 // 1024 tokens/chunk
    const int* srow = seq + (size_t)b * SEQLEN + (size_t)chunk * TPC;
    const int sub = tid & 3;                              // which float4 of the row
    const int tok = tid >> 2;                             // token slot 0..63

    float rx = 0.f, ry = 0.f, rz = 0.f, rw = 0.f;
#pragma unroll
    for (int i = 0; i < TPC / 64; ++i) {                  // 16 iters
        const int idx = srow[i * 64 + tok];               // 4 lanes share one addr
        const float4 c = ((const float4*)(ctab + (size_t)idx * HIDDEN))[sub];
        rx += c.x; ry += c.y; rz += c.z; rw += c.w;
    }

    // reduce over lanes with equal sub (bits 2..5 of lane id)
#pragma unroll
    for (int off = 4; off < 64; off <<= 1) {
        rx += __shfl_xor(rx, off, 64);
        ry += __shfl_xor(ry, off, 64);
        rz += __shfl_xor(rz, off, 64);
        rw += __shfl_xor(rw, off, 64);
    }

    __shared__ float red[4][16];
    const int lane = tid & 63, wave = tid >> 6;
    if (lane < 4) {                                       // lane == sub here
        red[wave][lane * 4 + 0] = rx;
        red[wave][lane * 4 + 1] = ry;
        red[wave][lane * 4 + 2] = rz;
        red[wave][lane * 4 + 3] = rw;
    }
    __syncthreads();
    if (tid < 16) {
        atomicAdd(&mem_acc[(size_t)b * HIDDEN + tid],
                  red[0][tid] + red[1][tid] + red[2][tid] + red[3][tid]);
    }
}

// ---------------------------------------------------------------------------
// K3: out[b][v] = memory[b] . Wo[:,v] + bo[v]  — write-BW bound (51.5 MB).
// memory rows are addressed with ONLY block-uniform indices → compiler emits
// scalar loads (s_load) + v_fma with SGPR broadcast operands. No LDS at all:
// avoids the per-wave ds_read broadcast storm (≈15 µs LDS-issue floor).
// ---------------------------------------------------------------------------
__global__ __launch_bounds__(256) void k3_output(
    const float* __restrict__ mem_acc, const float* __restrict__ Wo,
    const float* __restrict__ bo,      float* __restrict__ out)
{
    const int tid = threadIdx.x;
    const int b0 = blockIdx.y * K3_BCHUNK;
    const int v = blockIdx.x * 256 + tid;
    if (v >= VOCAB) return;

    float w[16];
#pragma unroll
    for (int h = 0; h < 16; ++h) w[h] = Wo[(size_t)h * VOCAB + v];
    const float bias = bo[v];

    float* orow = out + (size_t)b0 * VOCAB + v;
    const float* mrow = mem_acc + (size_t)b0 * HIDDEN;    // block-uniform base
#pragma unroll 4
    for (int bl = 0; bl < K3_BCHUNK; ++bl) {
        float acc = bias;
#pragma unroll
        for (int h = 0; h < 16; ++h)
            acc = fmaf(mrow[bl * HIDDEN + h], w[h], acc); // uniform addr → s_load
        orow[(size_t)bl * VOCAB] = acc;
    }
}

extern "C" void kernel_launch(void* const* d_in, const int* in_sizes, int n_in,
                              void* d_out, int out_size, void* d_ws, size_t ws_size,
                              hipStream_t stream) {
    const int*   seq   = (const int*)  d_in[0];   // [B, T] int32
    const float* embed = (const float*)d_in[1];   // [V, 16]
    const float* Wg    = (const float*)d_in[2];   // [16, 1]
    const float* bg    = (const float*)d_in[3];   // [1]
    const float* Wu    = (const float*)d_in[4];   // [16, 16]
    const float* bu    = (const float*)d_in[5];   // [16]
    const float* Wo    = (const float*)d_in[6];   // [16, V]
    const float* bo    = (const float*)d_in[7];   // [V]
    float* out = (float*)d_out;                   // [B, V] fp32

    float* ctab    = (float*)d_ws;                         // V*16 floats (3.2 MB)
    float* mem_acc = ctab + (size_t)VOCAB * HIDDEN;        // B*16 floats

    k1_build_table<<<dim3((VOCAB + 255) / 256), 256, 0, stream>>>(
        embed, Wg, bg, Wu, bu, ctab, mem_acc);
    k2_accum<<<dim3(BATCH, TCHUNKS), 256, 0, stream>>>(seq, ctab, mem_acc);
    k3_output<<<dim3((VOCAB + 255) / 256, BATCH / K3_BCHUNK), 256, 0, stream>>>(
        mem_acc, Wo, bo, out);
}